// Round 1
// baseline (189.888 us; speedup 1.0000x reference)
//
#include <hip/hip_runtime.h>

#define N_IN   128
#define LAYERS 6
#define N_H    320
#define DEG    32
#define N_OUT  18
#define N_TOTAL (N_IN + LAYERS * N_H)   // 2048
#define BB     4                        // batch elements per block

__device__ __forceinline__ float fast_tanh(float x) {
    // tanh(x) = 1 - 2/(exp(2x)+1); exact at +/-inf limits, ~1e-6 abs error
    float e = __expf(2.0f * x);
    return 1.0f - 2.0f * __builtin_amdgcn_rcpf(e + 1.0f);
}

__global__ __launch_bounds__(N_H) void policy_kernel(
    const float* __restrict__ obs,      // [B][N_IN]
    const int*   __restrict__ hid_src,  // [L][N_H][DEG]
    const float* __restrict__ hid_w,    // [L][N_H][DEG]
    const float* __restrict__ hid_b,    // [L][N_H]
    const int*   __restrict__ out_src,  // [N_OUT][DEG]
    const float* __restrict__ out_w,    // [N_OUT][DEG]
    const float* __restrict__ out_b,    // [N_OUT]
    float*       __restrict__ out)      // [B][N_OUT]
{
    // acts[row][b] : activation vector for BB batch elements, transposed so a
    // batch-invariant gather index becomes one 16B ds_read_b128 per lane.
    __shared__ float acts[N_TOTAL * BB];   // 32 KB -> 5 blocks/CU

    const int tid = threadIdx.x;
    const int b0  = blockIdx.x * BB;

    // Stage obs -> acts[0..N_IN)[0..BB)
    for (int idx = tid; idx < N_IN * BB; idx += N_H) {
        int j = idx >> 7;            // batch slot (N_IN == 128)
        int i = idx & (N_IN - 1);    // feature — consecutive tids coalesce on global read
        acts[i * BB + j] = obs[(b0 + j) * N_IN + i];
    }
    __syncthreads();

    const int n = tid;  // one hidden unit per thread (blockDim == N_H)

    for (int l = 0; l < LAYERS; ++l) {
        const int4*   src4 = (const int4*)  (hid_src + (l * N_H + n) * DEG);
        const float4* w4   = (const float4*)(hid_w   + (l * N_H + n) * DEG);
        float ax = 0.f, ay = 0.f, az = 0.f, aw = 0.f;
        #pragma unroll
        for (int q = 0; q < DEG / 4; ++q) {
            int4   s = src4[q];
            float4 w = w4[q];
            float4 a0 = *(const float4*)(acts + s.x * BB);
            float4 a1 = *(const float4*)(acts + s.y * BB);
            float4 a2 = *(const float4*)(acts + s.z * BB);
            float4 a3 = *(const float4*)(acts + s.w * BB);
            ax += a0.x * w.x + a1.x * w.y + a2.x * w.z + a3.x * w.w;
            ay += a0.y * w.x + a1.y * w.y + a2.y * w.z + a3.y * w.w;
            az += a0.z * w.x + a1.z * w.y + a2.z * w.z + a3.z * w.w;
            aw += a0.w * w.x + a1.w * w.y + a2.w * w.z + a3.w * w.w;
        }
        float bias = hid_b[l * N_H + n];
        float4 h;
        h.x = fast_tanh(ax + bias);
        h.y = fast_tanh(ay + bias);
        h.z = fast_tanh(az + bias);
        h.w = fast_tanh(aw + bias);
        // writes go to rows [N_IN + l*N_H, ...) which this layer never reads,
        // so a single barrier at end of layer is sufficient.
        *(float4*)(acts + (N_IN + l * N_H + n) * BB) = h;
        __syncthreads();
    }

    // Output layer: 18 units
    if (n < N_OUT) {
        const int4*   src4 = (const int4*)  (out_src + n * DEG);
        const float4* w4   = (const float4*)(out_w   + n * DEG);
        float ax = 0.f, ay = 0.f, az = 0.f, aw = 0.f;
        #pragma unroll
        for (int q = 0; q < DEG / 4; ++q) {
            int4   s = src4[q];
            float4 w = w4[q];
            float4 a0 = *(const float4*)(acts + s.x * BB);
            float4 a1 = *(const float4*)(acts + s.y * BB);
            float4 a2 = *(const float4*)(acts + s.z * BB);
            float4 a3 = *(const float4*)(acts + s.w * BB);
            ax += a0.x * w.x + a1.x * w.y + a2.x * w.z + a3.x * w.w;
            ay += a0.y * w.x + a1.y * w.y + a2.y * w.z + a3.y * w.w;
            az += a0.z * w.x + a1.z * w.y + a2.z * w.z + a3.z * w.w;
            aw += a0.w * w.x + a1.w * w.y + a2.w * w.z + a3.w * w.w;
        }
        float bias = out_b[n];
        out[(b0 + 0) * N_OUT + n] = fast_tanh(ax + bias);
        out[(b0 + 1) * N_OUT + n] = fast_tanh(ay + bias);
        out[(b0 + 2) * N_OUT + n] = fast_tanh(az + bias);
        out[(b0 + 3) * N_OUT + n] = fast_tanh(aw + bias);
    }
}

extern "C" void kernel_launch(void* const* d_in, const int* in_sizes, int n_in,
                              void* d_out, int out_size, void* d_ws, size_t ws_size,
                              hipStream_t stream) {
    const float* obs     = (const float*)d_in[0];
    const int*   hid_src = (const int*)  d_in[1];
    const float* hid_w   = (const float*)d_in[2];
    const float* hid_b   = (const float*)d_in[3];
    const int*   out_src = (const int*)  d_in[4];
    const float* out_w   = (const float*)d_in[5];
    const float* out_b   = (const float*)d_in[6];
    float* out = (float*)d_out;

    const int batch = in_sizes[0] / N_IN;   // 8192
    policy_kernel<<<batch / BB, N_H, 0, stream>>>(
        obs, hid_src, hid_w, hid_b, out_src, out_w, out_b, out);
}